// Round 12
// baseline (433.748 us; speedup 1.0000x reference)
//
#include <hip/hip_runtime.h>
#include <stdint.h>

#define NN 100000
#define EE 800000
#define GEMM_BX 1563          // ceil(100000/64)
#define WSTR 72               // padded bf16 LDS row stride (144 B: 2-way bank aliasing = free)
#define SLAB ((size_t)NN * 64)
#define EDGE_CAP 2304         // lW bytes / 4 — LDS edge-index capacity (mean ~358/block)

// megaA: count (3125) ⊕ input inst{0,1,2} (4689) interleaved 1:1, + prep (128)
#define MA_TOTAL 7942
// megaB: fill (3125) ⊕ input inst{3,4} (3126) interleaved 1:1
#define MB_TOTAL 6251

typedef unsigned short u16;
typedef __attribute__((ext_vector_type(8))) short bf16x8;   // 8 bf16 = 4 VGPRs
typedef __attribute__((ext_vector_type(4))) float f32x4;

// f32 -> bf16 RNE
__device__ __forceinline__ uint32_t f2bf(float f) {
  uint32_t u = __float_as_uint(f);
  return (u + 0x7fffu + ((u >> 16) & 1u)) >> 16;
}

// ============================ threefry / noise ============================
__device__ __forceinline__ void tf_round(uint32_t& x0, uint32_t& x1, int r) {
  x0 += x1;
  x1 = (x1 << r) | (x1 >> (32 - r));
  x1 ^= x0;
}

// threefry2x32 with key (0, 42) == jax.random.key(42)
__device__ __forceinline__ void threefry_0_42(uint32_t c0, uint32_t c1,
                                              uint32_t& o0, uint32_t& o1) {
  const uint32_t ks0 = 0u, ks1 = 42u, ks2 = 0x1BD11BDAu ^ 42u;
  uint32_t x0 = c0 + ks0, x1 = c1 + ks1;
  tf_round(x0, x1, 13); tf_round(x0, x1, 15); tf_round(x0, x1, 26); tf_round(x0, x1, 6);
  x0 += ks1; x1 += ks2 + 1u;
  tf_round(x0, x1, 17); tf_round(x0, x1, 29); tf_round(x0, x1, 16); tf_round(x0, x1, 24);
  x0 += ks2; x1 += ks0 + 2u;
  tf_round(x0, x1, 13); tf_round(x0, x1, 15); tf_round(x0, x1, 26); tf_round(x0, x1, 6);
  x0 += ks0; x1 += ks1 + 3u;
  tf_round(x0, x1, 17); tf_round(x0, x1, 29); tf_round(x0, x1, 16); tf_round(x0, x1, 24);
  x0 += ks1; x1 += ks2 + 4u;
  tf_round(x0, x1, 13); tf_round(x0, x1, 15); tf_round(x0, x1, 26); tf_round(x0, x1, 6);
  x0 += ks2; x1 += ks0 + 5u;
  o0 = x0; o1 = x1;
}

// jax_threefry_partitionable noise (verified R2): bits = o0^o1 of threefry((0,42),(0,f))
__device__ __forceinline__ float noise_val(int s, int n, int d) {
  uint32_t f = (uint32_t)s * 6400000u + (uint32_t)n * 64u + (uint32_t)d;
  uint32_t o0, o1;
  threefry_0_42(0u, f, o0, o1);
  uint32_t bits = o0 ^ o1;
  float v = __uint_as_float((bits >> 9) | 0x3f800000u) - 1.0f;
  const float LO = -0.99999994f;
  float u = v * 2.0f + LO;
  u = fmaxf(u, LO);
  float w = -__logf(fmaf(-u, u, 1.0f));
  float ww = w - 2.5f;
  float p = 2.81022636e-08f;
  p = fmaf(p, ww, 3.43273939e-07f);
  p = fmaf(p, ww, -3.5233877e-06f);
  p = fmaf(p, ww, -4.39150654e-06f);
  p = fmaf(p, ww, 0.00021858087f);
  p = fmaf(p, ww, -0.00125372503f);
  p = fmaf(p, ww, -0.00417768164f);
  p = fmaf(p, ww, 0.246640727f);
  p = fmaf(p, ww, 1.50140941f);
  if (__any(w >= 5.0f)) {
    float ws = sqrtf(w) - 3.0f;
    float p2 = -0.000200214257f;
    p2 = fmaf(p2, ws, 0.000100950558f);
    p2 = fmaf(p2, ws, 0.00134934322f);
    p2 = fmaf(p2, ws, -0.00367342844f);
    p2 = fmaf(p2, ws, 0.00573950773f);
    p2 = fmaf(p2, ws, -0.0076224613f);
    p2 = fmaf(p2, ws, 0.00943887047f);
    p2 = fmaf(p2, ws, 1.00167406f);
    p2 = fmaf(p2, ws, 2.83297682f);
    p = (w < 5.0f) ? p : p2;
  }
  return 0.141421356f * (p * u);   // 0.1 * sqrt(2) * erfinv(u)
}

// ============================ mask dtype detection ============================
__device__ __forceinline__ int mask_at(const void* m, int e, int mode) {
  if (mode == 0) return ((const int*)m)[e] != 0;
  if (mode == 1) return ((const unsigned char*)m)[e] != 0;
  return ((const float*)m)[e] != 0.0f;
}

// ============================ pre: detect + WiT/WfT transpose + C1 ============================
__global__ void k_pre(const unsigned* mw, int* mode_out,
                      const float* Wi, const float* Wf,
                      const float* msg_b, const float* upd_W,
                      u16* WiT, u16* WfT, float* C1) {
  int b = blockIdx.x, t = threadIdx.x;
  if (b == 0) {
    __shared__ int nonbin, nonfloat;
    if (t == 0) { nonbin = 0; nonfloat = 0; }
    __syncthreads();
    int lb = 0, lf = 0;
    for (int i = t; i < 4096; i += 256) {
      unsigned v = mw[i];
      if (v > 1u) lb = 1;
      if (v != 0u && v != 0x3F800000u) lf = 1;
    }
    if (lb) atomicOr(&nonbin, 1);
    if (lf) atomicOr(&nonfloat, 1);
    __syncthreads();
    if (t == 0)
      mode_out[0] = (nonbin == 0) ? 0 : ((nonfloat == 0) ? 2 : 1);
    return;
  }
  if (b <= 2) {
    const float* W = (b == 1) ? Wi : Wf;
    u16* WT = (b == 1) ? WiT : WfT;
    for (int o = t; o < 4096; o += 256) {
      int k = o >> 6, n = o & 63;
      WT[n * 64 + k] = (u16)f2bf(W[k * 64 + n]);
    }
    return;
  }
  int l = b - 3;                      // 0,1
  const float* Wu2 = upd_W + l * 8192 + 4096;
  if (t < 64) {
    float acc = 0.f;
    for (int j = 0; j < 64; ++j) acc = fmaf(msg_b[l * 64 + j], Wu2[j * 64 + t], acc);
    C1[l * 64 + t] = acc;
  }
}

// ============================ CSR scans ============================
__global__ void k_scan_a(const int* cnt, int* blockSums) {
  __shared__ int sd[256];
  int t = threadIdx.x;
  int base = blockIdx.x * 1024 + t * 4;
  int s = 0;
  #pragma unroll
  for (int j = 0; j < 4; ++j) {
    int i = base + j;
    if (i < NN) s += cnt[i];
  }
  sd[t] = s;
  __syncthreads();
  for (int off = 128; off > 0; off >>= 1) {
    if (t < off) sd[t] += sd[t + off];
    __syncthreads();
  }
  if (t == 0) blockSums[blockIdx.x] = sd[0];
}

__global__ void k_scan_b(int* blockSums, int nb, int* total_out) {
  __shared__ int sd[128];
  int t = threadIdx.x;
  int v = (t < nb) ? blockSums[t] : 0;
  sd[t] = v;
  __syncthreads();
  for (int off = 1; off < 128; off <<= 1) {
    int x = (t >= off) ? sd[t - off] : 0;
    __syncthreads();
    sd[t] += x;
    __syncthreads();
  }
  if (t < nb) blockSums[t] = sd[t] - v;
  if (t == 0) total_out[0] = sd[127];
}

__global__ void k_scan_c(const int* cnt, const int* blockOffs, int* row_ptr,
                         int* cursor, float* cinv) {
  __shared__ int sd[256];
  int t = threadIdx.x;
  int base = blockIdx.x * 1024 + t * 4;
  int v[4], s = 0;
  #pragma unroll
  for (int j = 0; j < 4; ++j) {
    int i = base + j;
    v[j] = (i < NN) ? cnt[i] : 0;
    s += v[j];
  }
  sd[t] = s;
  __syncthreads();
  for (int off = 1; off < 256; off <<= 1) {
    int x = (t >= off) ? sd[t - off] : 0;
    __syncthreads();
    sd[t] += x;
    __syncthreads();
  }
  int excl = sd[t] - s + blockOffs[blockIdx.x];
  #pragma unroll
  for (int j = 0; j < 4; ++j) {
    int i = base + j;
    if (i < NN) {
      row_ptr[i] = excl;
      cursor[i] = excl;
      cinv[i] = 1.0f / fmaxf((float)v[j], 1.0f);
    }
    excl += v[j];
  }
}

// ============================ MFMA helpers ============================
// Wave w owns rows [w*16, w*16+16). A-frag: A[m=lane&15][k=quad*8+j].
// B-frag from padded LDS. C/D: col=lane&15 (+nt*16), row=quad*4+reg.
__device__ __forceinline__ void mm4(const u16* lW, int m16, int q,
                                    bf16x8 a0, bf16x8 a1, f32x4 (&acc)[4]) {
  #pragma unroll
  for (int nt = 0; nt < 4; ++nt) {
    const u16* wp = lW + (nt * 16 + m16) * WSTR + q * 8;
    bf16x8 b0 = *(const bf16x8*)(wp);
    bf16x8 b1 = *(const bf16x8*)(wp + 32);
    acc[nt] = __builtin_amdgcn_mfma_f32_16x16x32_bf16(a0, b0, acc[nt], 0, 0, 0);
    acc[nt] = __builtin_amdgcn_mfma_f32_16x16x32_bf16(a1, b1, acc[nt], 0, 0, 0);
  }
}

// stage 64x64 bf16 weight (unpadded global) into padded LDS (stride WSTR)
__device__ __forceinline__ void stage_W(const u16* __restrict__ WT, u16* lW) {
  int t = threadIdx.x;
  int r = t >> 2, seg = (t & 3) * 16;
  const uint4* p = (const uint4*)(WT + r * 64 + seg);
  uint4 a = p[0], b = p[1];
  *(uint4*)(lW + r * WSTR + seg) = a;
  *(uint4*)(lW + r * WSTR + seg + 8) = b;
}

// ============================ input projection block (register-direct) ============================
// Thread t computes exactly ITS MFMA A-fragment elements: row arow=w*16+m16,
// k-segments [q*8, q*8+8) and [q*8+32, q*8+40) — no lT stage, no transpose.
__device__ __forceinline__ void input_block(int tile, int inst,
                                            const float* __restrict__ x,
                                            const u16* __restrict__ WiT,
                                            const float* __restrict__ bi,
                                            u16* __restrict__ HoutB,
                                            u16* lW, float* lB) {
  int t = threadIdx.x;
  stage_W(WiT, lW);
  if (t < 64) lB[t] = bi[t];
  int R0 = tile * 64;
  int l = t & 63, w = t >> 6;
  int m16 = l & 15, q = l >> 4;
  int arow = w * 16 + m16;
  int gra = R0 + arow;
  float v[16];
  if (gra < NN) {
    const float4* p0 = (const float4*)(x + (size_t)gra * 64 + q * 8);
    const float4* p1 = (const float4*)(x + (size_t)gra * 64 + q * 8 + 32);
    float4 a = p0[0], b = p0[1], c = p1[0], d = p1[1];
    v[0] = a.x;  v[1] = a.y;  v[2] = a.z;  v[3] = a.w;
    v[4] = b.x;  v[5] = b.y;  v[6] = b.z;  v[7] = b.w;
    v[8] = c.x;  v[9] = c.y;  v[10] = c.z; v[11] = c.w;
    v[12] = d.x; v[13] = d.y; v[14] = d.z; v[15] = d.w;
    if (inst > 0) {
      int s = inst - 1;
      #pragma unroll
      for (int j = 0; j < 8; ++j) v[j] += noise_val(s, gra, q * 8 + j);
      #pragma unroll
      for (int j = 0; j < 8; ++j) v[8 + j] += noise_val(s, gra, q * 8 + 32 + j);
    }
  } else {
    #pragma unroll
    for (int j = 0; j < 16; ++j) v[j] = 0.f;
  }
  union UB { uint32_t u[4]; bf16x8 vv; };
  UB ua, ub;
  #pragma unroll
  for (int jj = 0; jj < 4; ++jj) {
    ua.u[jj] = f2bf(v[2 * jj]) | (f2bf(v[2 * jj + 1]) << 16);
    ub.u[jj] = f2bf(v[8 + 2 * jj]) | (f2bf(v[8 + 2 * jj + 1]) << 16);
  }
  __syncthreads();   // lW staged
  f32x4 acc[4] = {{0.f, 0.f, 0.f, 0.f}, {0.f, 0.f, 0.f, 0.f},
                  {0.f, 0.f, 0.f, 0.f}, {0.f, 0.f, 0.f, 0.f}};
  mm4(lW, m16, q, ua.vv, ub.vv, acc);
  u16* Hout = HoutB + (size_t)inst * SLAB;
  #pragma unroll
  for (int nt = 0; nt < 4; ++nt) {
    int c = nt * 16 + m16;
    #pragma unroll
    for (int r_ = 0; r_ < 4; ++r_) {
      int row = w * 16 + q * 4 + r_;
      int gr = R0 + row;
      if (gr < NN) {
        float z = fmaxf(acc[nt][r_] + lB[c], 0.f);
        Hout[(size_t)gr * 64 + c] = (u16)f2bf(z);
      }
    }
  }
}

// ============================ megaA: count ⊕ input{0,1,2} ⊕ prep ============================
// Count (memory/atomic) and input (VALU noise) interleaved 1:1 by blockIdx so
// both are co-resident throughout — different pipes overlap (m114).
__global__ __launch_bounds__(256) void k_megaA(
    const void* __restrict__ mask, const int* __restrict__ dst,
    int* __restrict__ cnt, const int* __restrict__ mode_p,
    const float* __restrict__ x, const u16* __restrict__ WiT,
    const float* __restrict__ bi, u16* __restrict__ HoutB,
    const float* __restrict__ msg_W, const float* __restrict__ upd_W,
    u16* __restrict__ Wu1T, u16* __restrict__ A1T, u16* __restrict__ A2T) {
  __shared__ __align__(16) u16 lW[64 * WSTR];
  __shared__ float lB[64];
  int t = threadIdx.x;
  int bid = blockIdx.x;

  int idx = -1;
  if (bid < 6250) {
    if ((bid & 1) == 0) {                    // ---- edge count ----
      int e = (bid >> 1) * 256 + t;
      if (e < EE && mask_at(mask, e, *mode_p)) atomicAdd(&cnt[dst[e]], 1);
      return;
    }
    idx = bid >> 1;                          // input 0..3124
  } else if (bid < 7814) {
    idx = 3125 + (bid - 6250);               // input 3125..4688 (inst 2 tail)
  }
  if (idx >= 0) {
    input_block(idx % GEMM_BX, idx / GEMM_BX, x, WiT, bi, HoutB, lW, lB);
    return;
  }
  // ---- A1T/A2T/Wu1T fold (split-K), 128 blocks ----
  int blk = bid - 7814;
  int l = blk >> 6, b = blk & 63;
  const float* WmT = msg_W + l * 8192;
  const float* WmB = WmT + 4096;
  const float* Wu1 = upd_W + l * 8192;
  const float* Wu2 = Wu1 + 4096;
  float* sd1 = (float*)lW;                   // alias: 2 KB of lW
  float* sd2 = sd1 + 256;
  int a = t & 63, part = t >> 6;
  float a1 = 0.f, a2 = 0.f;
  #pragma unroll
  for (int jj = 0; jj < 16; ++jj) {
    int j = part * 16 + jj;
    float w2 = Wu2[j * 64 + b];
    a1 = fmaf(WmT[a * 64 + j], w2, a1);
    a2 = fmaf(WmB[a * 64 + j], w2, a2);
  }
  sd1[part * 64 + a] = a1;
  sd2[part * 64 + a] = a2;
  __syncthreads();
  if (t < 64) {
    float s1 = sd1[t] + sd1[64 + t] + sd1[128 + t] + sd1[192 + t];
    float s2 = sd2[t] + sd2[64 + t] + sd2[128 + t] + sd2[192 + t];
    int o = l * 4096 + b * 64 + t;
    A1T[o] = (u16)f2bf(s1);
    A2T[o] = (u16)f2bf(s2);
    Wu1T[o] = (u16)f2bf(Wu1[t * 64 + b]);
  }
}

// ============================ megaB: fill ⊕ input{3,4} ============================
// Fill (atomic/scatter) hidden under the remaining 2 instances of noise VALU.
__global__ __launch_bounds__(256) void k_megaB(
    const void* __restrict__ mask, const int* __restrict__ src,
    const int* __restrict__ dst, int* __restrict__ cursor,
    int* __restrict__ col, const int* __restrict__ mode_p,
    const float* __restrict__ x, const u16* __restrict__ WiT,
    const float* __restrict__ bi, u16* __restrict__ HoutB) {
  __shared__ __align__(16) u16 lW[64 * WSTR];
  __shared__ float lB[64];
  int t = threadIdx.x;
  int bid = blockIdx.x;

  int idx;
  if (bid < 6250) {
    if ((bid & 1) == 0) {                    // ---- CSR fill ----
      int e = (bid >> 1) * 256 + t;
      if (e < EE && mask_at(mask, e, *mode_p)) {
        int p = atomicAdd(&cursor[dst[e]], 1);
        col[p] = src[e];
      }
      return;
    }
    idx = bid >> 1;                          // 0..3124
  } else {
    idx = 3125;                              // bid == 6250
  }
  int g = 4689 + idx;                        // input inst{3,4}: 4689..7814
  input_block(g % GEMM_BX, g / GEMM_BX, x, WiT, bi, HoutB, lW, lB);
}

// ============================ layer (2 instances/block, R2-champion) ============================
__global__ __launch_bounds__(256) void k_layer(const u16* __restrict__ HinB,
                                               u16* __restrict__ HoutB,
                                               const int* __restrict__ row_ptr,
                                               const int* __restrict__ col,
                                               const float* __restrict__ cinv,
                                               const u16* __restrict__ Wu1T,
                                               const u16* __restrict__ A1T,
                                               const u16* __restrict__ A2T,
                                               const float* __restrict__ b0,
                                               const float* __restrict__ c1) {
  __shared__ __align__(16) u16 lS0[64 * WSTR];
  __shared__ __align__(16) u16 lS1[64 * WSTR];
  __shared__ __align__(16) u16 lW[64 * WSTR];   // aliased as edge-index buffer pre-GEMM
  __shared__ float lB[128];
  __shared__ float lG[64];
  __shared__ int   lRP[65];
  int* lEdge = (int*)lW;                         // EDGE_CAP ints

  int t = threadIdx.x;
  int R0 = blockIdx.x * 64;
  int instBase = blockIdx.y * 2;
  bool two = (instBase + 1) < 5;
  const u16* Hin0 = HinB + (size_t)instBase * SLAB;
  const u16* Hin1 = Hin0 + (two ? SLAB : 0);
  u16* Hout0 = HoutB + (size_t)instBase * SLAB;
  u16* Hout1 = Hout0 + SLAB;

  if (t < 65) {
    int idx = R0 + t;
    if (idx > NN) idx = NN;
    lRP[t] = row_ptr[idx];
  }
  if (t < 64) {
    lB[t] = b0[t];
    lB[64 + t] = c1[t];
  }
  __syncthreads();

  int e0 = lRP[0];
  int nE = lRP[64] - e0;
  bool inLds = (nE <= EDGE_CAP);
  if (inLds) {
    for (int i = t; i < nE; i += 256) lEdge[i] = col[e0 + i];
  }
  if (t < 64) lG[t] = (lRP[t + 1] > lRP[t]) ? 1.f : 0.f;
  __syncthreads();

  // ---- gather: 8 lanes per row (uint4 = 16 B/lane), 32 rows per pass ----
  {
    int sub = t >> 3, lane8 = t & 7;
    int f0 = lane8 * 8;                       // u16 offset (16 B segment)
    const u16* hb0 = Hin0 + f0;
    const u16* hb1 = Hin1 + f0;
    #pragma unroll
    for (int bb = 0; bb < 2; ++bb) {
      int r = bb * 32 + sub;
      int n = R0 + r;
      float g[8], h[8];
      #pragma unroll
      for (int j = 0; j < 8; ++j) { g[j] = 0.f; h[j] = 0.f; }
      if (n < NN) {
        int e = lRP[r], end = lRP[r + 1];
        int last = end - 1;
        for (; e < end; e += 4) {
          int idx4[4];
          #pragma unroll
          for (int j = 0; j < 4; ++j) {
            int ee = e + j;
            ee = (ee < last) ? ee : last;
            idx4[j] = inLds ? lEdge[ee - e0] : col[ee];
          }
          uint4 P[4];
          #pragma unroll
          for (int j = 0; j < 4; ++j)
            P[j] = *(const uint4*)(hb0 + ((unsigned)idx4[j] << 6));
          uint4 Q[4];
          if (two) {
            #pragma unroll
            for (int j = 0; j < 4; ++j)
              Q[j] = *(const uint4*)(hb1 + ((unsigned)idx4[j] << 6));
          }
          #pragma unroll
          for (int j = 1; j < 4; ++j) {
            bool ok = (e + j) < end;
            P[j].x = ok ? P[j].x : 0u;
            P[j].y = ok ? P[j].y : 0u;
            P[j].z = ok ? P[j].z : 0u;
            P[j].w = ok ? P[j].w : 0u;
            if (two) {
              Q[j].x = ok ? Q[j].x : 0u;
              Q[j].y = ok ? Q[j].y : 0u;
              Q[j].z = ok ? Q[j].z : 0u;
              Q[j].w = ok ? Q[j].w : 0u;
            }
          }
          #pragma unroll
          for (int j = 0; j < 4; ++j) {
            uint4 v = P[j];
            g[0] += __uint_as_float(v.x << 16);
            g[1] += __uint_as_float(v.x & 0xffff0000u);
            g[2] += __uint_as_float(v.y << 16);
            g[3] += __uint_as_float(v.y & 0xffff0000u);
            g[4] += __uint_as_float(v.z << 16);
            g[5] += __uint_as_float(v.z & 0xffff0000u);
            g[6] += __uint_as_float(v.w << 16);
            g[7] += __uint_as_float(v.w & 0xffff0000u);
          }
          if (two) {
            #pragma unroll
            for (int j = 0; j < 4; ++j) {
              uint4 v = Q[j];
              h[0] += __uint_as_float(v.x << 16);
              h[1] += __uint_as_float(v.x & 0xffff0000u);
              h[2] += __uint_as_float(v.y << 16);
              h[3] += __uint_as_float(v.y & 0xffff0000u);
              h[4] += __uint_as_float(v.z << 16);
              h[5] += __uint_as_float(v.z & 0xffff0000u);
              h[6] += __uint_as_float(v.w << 16);
              h[7] += __uint_as_float(v.w & 0xffff0000u);
            }
          }
        }
        float ci = cinv[n];
        #pragma unroll
        for (int j = 0; j < 8; ++j) { g[j] *= ci; h[j] *= ci; }
      }
      uint4 pk;
      pk.x = f2bf(g[0]) | (f2bf(g[1]) << 16);
      pk.y = f2bf(g[2]) | (f2bf(g[3]) << 16);
      pk.z = f2bf(g[4]) | (f2bf(g[5]) << 16);
      pk.w = f2bf(g[6]) | (f2bf(g[7]) << 16);
      *(uint4*)(lS0 + r * WSTR + f0) = pk;
      if (two) {
        uint4 pk2;
        pk2.x = f2bf(h[0]) | (f2bf(h[1]) << 16);
        pk2.y = f2bf(h[2]) | (f2bf(h[3]) << 16);
        pk2.z = f2bf(h[4]) | (f2bf(h[5]) << 16);
        pk2.w = f2bf(h[6]) | (f2bf(h[7]) << 16);
        *(uint4*)(lS1 + r * WSTR + f0) = pk2;
      }
    }
  }
  __syncthreads();   // lS0/lS1 done; lEdge dead — lW free for weights

  int l = t & 63, w = t >> 6;
  int m16 = l & 15, q = l >> 4;
  int arow = w * 16 + m16;
  int gra = R0 + arow;
  bf16x8 zz = {0, 0, 0, 0, 0, 0, 0, 0};
  bf16x8 fa0_0 = zz, fa1_0 = zz, fa0_1 = zz, fa1_1 = zz;
  if (gra < NN) {
    const u16* ap = Hin0 + (size_t)gra * 64 + q * 8;
    fa0_0 = *(const bf16x8*)(ap);
    fa1_0 = *(const bf16x8*)(ap + 32);
    if (two) {
      const u16* ap1 = Hin1 + (size_t)gra * 64 + q * 8;
      fa0_1 = *(const bf16x8*)(ap1);
      fa1_1 = *(const bf16x8*)(ap1 + 32);
    }
  }

  stage_W(Wu1T, lW);
  __syncthreads();

  float gA = lG[arow];
  f32x4 acc0[4] = {{0.f, 0.f, 0.f, 0.f}, {0.f, 0.f, 0.f, 0.f},
                   {0.f, 0.f, 0.f, 0.f}, {0.f, 0.f, 0.f, 0.f}};
  f32x4 acc1[4] = {{0.f, 0.f, 0.f, 0.f}, {0.f, 0.f, 0.f, 0.f},
                   {0.f, 0.f, 0.f, 0.f}, {0.f, 0.f, 0.f, 0.f}};
  mm4(lW, m16, q, fa0_0, fa1_0, acc0);            // H @ Wu1
  if (two) mm4(lW, m16, q, fa0_1, fa1_1, acc1);
  __syncthreads();
  stage_W(A1T, lW);
  __syncthreads();
  {
    bf16x8 ga0 = (gA != 0.f) ? fa0_0 : zz;
    bf16x8 ga1 = (gA != 0.f) ? fa1_0 : zz;
    mm4(lW, m16, q, ga0, ga1, acc0);              // g * (H @ A1)
    if (two) {
      bf16x8 gb0 = (gA != 0.f) ? fa0_1 : zz;
      bf16x8 gb1 = (gA != 0.f) ? fa1_1 : zz;
      mm4(lW, m16, q, gb0, gb1, acc1);
    }
  }
  __syncthreads();
  stage_W(A2T, lW);
  __syncthreads();
  {
    const u16* sRow = lS0 + arow * WSTR + q * 8;
    bf16x8 fs0 = *(const bf16x8*)(sRow);
    bf16x8 fs1 = *(const bf16x8*)(sRow + 32);
    mm4(lW, m16, q, fs0, fs1, acc0);              // (cinv*S) @ A2
    if (two) {
      const u16* sRow1 = lS1 + arow * WSTR + q * 8;
      bf16x8 ft0 = *(const bf16x8*)(sRow1);
      bf16x8 ft1 = *(const bf16x8*)(sRow1 + 32);
      mm4(lW, m16, q, ft0, ft1, acc1);
    }
  }
  #pragma unroll
  for (int nt = 0; nt < 4; ++nt) {
    int c = nt * 16 + m16;
    #pragma unroll
    for (int r_ = 0; r_ < 4; ++r_) {
      int row = w * 16 + q * 4 + r_;
      int gr = R0 + row;
      if (gr < NN) {
        float bias = lB[c] + lG[row] * lB[64 + c];
        float v0 = fmaxf(acc0[nt][r_] + bias, 0.f);
        Hout0[(size_t)gr * 64 + c] = (u16)f2bf(v0);
        if (two) {
          float v1 = fmaxf(acc1[nt][r_] + bias, 0.f);
          Hout1[(size_t)gr * 64 + c] = (u16)f2bf(v1);
        }
      }
    }
  }
}

// ============================ final projection + variance (register-direct A-frags) ============================
__global__ __launch_bounds__(256) void k_final(const u16* __restrict__ HinB,
                                               const u16* __restrict__ WfT,
                                               const float* __restrict__ bfv,
                                               float* __restrict__ outCausal,
                                               float* __restrict__ out_u) {
  __shared__ __align__(16) u16 lW[64 * WSTR];
  __shared__ float lB[64];
  int t = threadIdx.x;
  int R0 = blockIdx.x * 64;
  stage_W(WfT, lW);
  if (t < 64) lB[t] = bfv[t];
  int l = t & 63, w = t >> 6;
  int m16 = l & 15, q = l >> 4;
  int arow = w * 16 + m16;
  int gra = R0 + arow;
  bf16x8 zz = {0, 0, 0, 0, 0, 0, 0, 0};
  float s1[16], s2[16];
  #pragma unroll
  for (int j = 0; j < 16; ++j) { s1[j] = 0.f; s2[j] = 0.f; }
  __syncthreads();   // lW staged

  for (int inst = 0; inst < 5; ++inst) {
    bf16x8 fa0 = zz, fa1 = zz;
    if (gra < NN) {
      const u16* ap = HinB + (size_t)inst * SLAB + (size_t)gra * 64 + q * 8;
      fa0 = *(const bf16x8*)(ap);
      fa1 = *(const bf16x8*)(ap + 32);
    }
    f32x4 acc[4] = {{0.f, 0.f, 0.f, 0.f}, {0.f, 0.f, 0.f, 0.f},
                    {0.f, 0.f, 0.f, 0.f}, {0.f, 0.f, 0.f, 0.f}};
    mm4(lW, m16, q, fa0, fa1, acc);
    #pragma unroll
    for (int nt = 0; nt < 4; ++nt) {
      int c = nt * 16 + m16;
      #pragma unroll
      for (int r_ = 0; r_ < 4; ++r_) {
        float z = acc[nt][r_] + lB[c];
        if (inst == 0) {
          int gr = R0 + w * 16 + q * 4 + r_;
          if (gr < NN) outCausal[(size_t)gr * 64 + c] = z;
        } else {
          s1[nt * 4 + r_] += z;
          s2[nt * 4 + r_] = fmaf(z, z, s2[nt * 4 + r_]);
        }
      }
    }
  }
  #pragma unroll
  for (int r_ = 0; r_ < 4; ++r_) {
    float pr = 0.f;
    #pragma unroll
    for (int nt = 0; nt < 4; ++nt) {
      float a = s1[nt * 4 + r_];
      pr += s2[nt * 4 + r_] - 0.25f * a * a;
    }
    #pragma unroll
    for (int msk = 1; msk < 16; msk <<= 1)
      pr += __shfl_xor(pr, msk, 64);
    if (m16 == 0) {
      int gr = R0 + w * 16 + q * 4 + r_;
      if (gr < NN) out_u[gr] = fmaxf(pr * (1.0f / 3.0f), 1e-6f);
    }
  }
}

// ============================ launch ============================
extern "C" void kernel_launch(void* const* d_in, const int* in_sizes, int n_in,
                              void* d_out, int out_size, void* d_ws, size_t ws_size,
                              hipStream_t stream) {
  const float* x      = (const float*)d_in[0];
  const int*   eidx   = (const int*)d_in[1];
  const void*  mask   = d_in[2];
  const float* Wi     = (const float*)d_in[3];
  const float* bi     = (const float*)d_in[4];
  const float* msg_W  = (const float*)d_in[5];
  const float* msg_b  = (const float*)d_in[6];
  const float* upd_W  = (const float*)d_in[7];
  const float* upd_b  = (const float*)d_in[8];
  const float* Wf     = (const float*)d_in[9];
  const float* bfv    = (const float*)d_in[10];

  const int* src = eidx;
  const int* dst = eidx + EE;

  char* ws = (char*)d_ws;
  size_t off = 0;
  auto alloc = [&](size_t bytes) -> void* {
    void* p = ws + off;
    off += (bytes + 255) & ~(size_t)255;
    return p;
  };

  int*   cnt     = (int*)alloc(NN * sizeof(int));
  float* cinv    = (float*)alloc(NN * sizeof(float));
  int*   row_ptr = (int*)alloc((NN + 1) * sizeof(int));
  int*   cursor  = (int*)alloc(NN * sizeof(int));
  int*   col     = (int*)alloc(EE * sizeof(int));
  int*   bsums   = (int*)alloc(128 * sizeof(int));
  int*   mode_p  = (int*)alloc(sizeof(int));
  u16*   Wu1T    = (u16*)alloc(2 * 4096 * sizeof(u16));
  u16*   A1T     = (u16*)alloc(2 * 4096 * sizeof(u16));
  u16*   A2T     = (u16*)alloc(2 * 4096 * sizeof(u16));
  u16*   WiT     = (u16*)alloc(4096 * sizeof(u16));
  u16*   WfT     = (u16*)alloc(4096 * sizeof(u16));
  float* C1      = (float*)alloc(2 * 64 * sizeof(float));
  u16*   HA      = (u16*)alloc(5 * SLAB * sizeof(u16));   // 64 MB
  u16*   HB      = (u16*)alloc(5 * SLAB * sizeof(u16));   // 64 MB

  float* out_causal = (float*)d_out;
  float* out_u      = (float*)d_out + SLAB;

  // ---- pre: detect + WiT/WfT transpose + C1 ----
  k_pre<<<5, 256, 0, stream>>>((const unsigned*)mask, mode_p, Wi, Wf,
                               msg_b, upd_W, WiT, WfT, C1);
  hipMemsetAsync(cnt, 0, NN * sizeof(int), stream);

  // ---- megaA: edge count ⊕ input{0,1,2} ⊕ weight fold ----
  k_megaA<<<MA_TOTAL, 256, 0, stream>>>(mask, dst, cnt, mode_p,
                                        x, WiT, bi, HA,
                                        msg_W, upd_W, Wu1T, A1T, A2T);

  // ---- CSR scans ----
  const int SCAN_BLKS = (NN + 1023) / 1024;  // 98
  k_scan_a<<<SCAN_BLKS, 256, 0, stream>>>(cnt, bsums);
  k_scan_b<<<1, 128, 0, stream>>>(bsums, SCAN_BLKS, row_ptr + NN);
  k_scan_c<<<SCAN_BLKS, 256, 0, stream>>>(cnt, bsums, row_ptr, cursor, cinv);

  // ---- megaB: CSR fill ⊕ input{3,4} ----
  k_megaB<<<MB_TOTAL, 256, 0, stream>>>(mask, src, dst, cursor, col, mode_p,
                                        x, WiT, bi, HA);

  // ---- 2 GNN layers (instance pairs) + fused final ----
  dim3 gl(GEMM_BX, 3);   // instance pairs {0,1},{2,3},{4}
  k_layer<<<gl, 256, 0, stream>>>(HA, HB, row_ptr, col, cinv,
                                  Wu1T, A1T, A2T, upd_b, C1);
  k_layer<<<gl, 256, 0, stream>>>(HB, HA, row_ptr, col, cinv,
                                  Wu1T + 4096, A1T + 4096, A2T + 4096,
                                  upd_b + 64, C1 + 64);
  k_final<<<GEMM_BX, 256, 0, stream>>>(HA, WfT, bfv, out_causal, out_u);

  (void)in_sizes; (void)n_in; (void)out_size; (void)ws_size;
}

// Round 13
// 426.298 us; speedup vs baseline: 1.0175x; 1.0175x over previous
//
#include <hip/hip_runtime.h>
#include <stdint.h>

#define NN 100000
#define EE 800000
#define GEMM_BX 1563          // ceil(100000/64)
#define WSTR 72               // padded bf16 LDS row stride (144 B: 2-way bank aliasing = free)
#define SLAB ((size_t)NN * 64)
#define EDGE_CAP 2304         // lW bytes / 4 — LDS edge-index capacity (mean ~358/block)

// k_mega: count (3125) ⊕ input (7815) interleaved 1:1 for the first 6250 blocks,
// then remaining input, then prep (128).
#define MG_TOTAL 11068

typedef unsigned short u16;
typedef __attribute__((ext_vector_type(8))) short bf16x8;   // 8 bf16 = 4 VGPRs
typedef __attribute__((ext_vector_type(4))) float f32x4;

// f32 -> bf16 RNE
__device__ __forceinline__ uint32_t f2bf(float f) {
  uint32_t u = __float_as_uint(f);
  return (u + 0x7fffu + ((u >> 16) & 1u)) >> 16;
}

// ============================ threefry / noise ============================
__device__ __forceinline__ void tf_round(uint32_t& x0, uint32_t& x1, int r) {
  x0 += x1;
  x1 = (x1 << r) | (x1 >> (32 - r));
  x1 ^= x0;
}

// threefry2x32 with key (0, 42) == jax.random.key(42)
__device__ __forceinline__ void threefry_0_42(uint32_t c0, uint32_t c1,
                                              uint32_t& o0, uint32_t& o1) {
  const uint32_t ks0 = 0u, ks1 = 42u, ks2 = 0x1BD11BDAu ^ 42u;
  uint32_t x0 = c0 + ks0, x1 = c1 + ks1;
  tf_round(x0, x1, 13); tf_round(x0, x1, 15); tf_round(x0, x1, 26); tf_round(x0, x1, 6);
  x0 += ks1; x1 += ks2 + 1u;
  tf_round(x0, x1, 17); tf_round(x0, x1, 29); tf_round(x0, x1, 16); tf_round(x0, x1, 24);
  x0 += ks2; x1 += ks0 + 2u;
  tf_round(x0, x1, 13); tf_round(x0, x1, 15); tf_round(x0, x1, 26); tf_round(x0, x1, 6);
  x0 += ks0; x1 += ks1 + 3u;
  tf_round(x0, x1, 17); tf_round(x0, x1, 29); tf_round(x0, x1, 16); tf_round(x0, x1, 24);
  x0 += ks1; x1 += ks2 + 4u;
  tf_round(x0, x1, 13); tf_round(x0, x1, 15); tf_round(x0, x1, 26); tf_round(x0, x1, 6);
  x0 += ks2; x1 += ks0 + 5u;
  o0 = x0; o1 = x1;
}

// jax_threefry_partitionable noise (verified R2): bits = o0^o1 of threefry((0,42),(0,f))
__device__ __forceinline__ float noise_val(int s, int n, int d) {
  uint32_t f = (uint32_t)s * 6400000u + (uint32_t)n * 64u + (uint32_t)d;
  uint32_t o0, o1;
  threefry_0_42(0u, f, o0, o1);
  uint32_t bits = o0 ^ o1;
  float v = __uint_as_float((bits >> 9) | 0x3f800000u) - 1.0f;
  const float LO = -0.99999994f;
  float u = v * 2.0f + LO;
  u = fmaxf(u, LO);
  float w = -__logf(fmaf(-u, u, 1.0f));
  float ww = w - 2.5f;
  float p = 2.81022636e-08f;
  p = fmaf(p, ww, 3.43273939e-07f);
  p = fmaf(p, ww, -3.5233877e-06f);
  p = fmaf(p, ww, -4.39150654e-06f);
  p = fmaf(p, ww, 0.00021858087f);
  p = fmaf(p, ww, -0.00125372503f);
  p = fmaf(p, ww, -0.00417768164f);
  p = fmaf(p, ww, 0.246640727f);
  p = fmaf(p, ww, 1.50140941f);
  if (__any(w >= 5.0f)) {
    float ws = sqrtf(w) - 3.0f;
    float p2 = -0.000200214257f;
    p2 = fmaf(p2, ws, 0.000100950558f);
    p2 = fmaf(p2, ws, 0.00134934322f);
    p2 = fmaf(p2, ws, -0.00367342844f);
    p2 = fmaf(p2, ws, 0.00573950773f);
    p2 = fmaf(p2, ws, -0.0076224613f);
    p2 = fmaf(p2, ws, 0.00943887047f);
    p2 = fmaf(p2, ws, 1.00167406f);
    p2 = fmaf(p2, ws, 2.83297682f);
    p = (w < 5.0f) ? p : p2;
  }
  return 0.141421356f * (p * u);   // 0.1 * sqrt(2) * erfinv(u)
}

// ============================ mask dtype detection ============================
__device__ __forceinline__ int mask_at(const void* m, int e, int mode) {
  if (mode == 0) return ((const int*)m)[e] != 0;
  if (mode == 1) return ((const unsigned char*)m)[e] != 0;
  return ((const float*)m)[e] != 0.0f;
}

// ============================ pre: detect + WiT/WfT transpose + C1 + cnt zero ============================
__global__ void k_pre(const unsigned* mw, int* mode_out,
                      const float* Wi, const float* Wf,
                      const float* msg_b, const float* upd_W,
                      u16* WiT, u16* WfT, float* C1, int* cnt) {
  int b = blockIdx.x, t = threadIdx.x;
  if (b >= 5) {                       // ---- zero cnt (blocks 5..102) ----
    int base = (b - 5) * 1024 + t * 4;
    #pragma unroll
    for (int j = 0; j < 4; ++j) {
      int i = base + j;
      if (i < NN) cnt[i] = 0;
    }
    return;
  }
  if (b == 0) {
    __shared__ int nonbin, nonfloat;
    if (t == 0) { nonbin = 0; nonfloat = 0; }
    __syncthreads();
    int lb = 0, lf = 0;
    for (int i = t; i < 4096; i += 256) {
      unsigned v = mw[i];
      if (v > 1u) lb = 1;
      if (v != 0u && v != 0x3F800000u) lf = 1;
    }
    if (lb) atomicOr(&nonbin, 1);
    if (lf) atomicOr(&nonfloat, 1);
    __syncthreads();
    if (t == 0)
      mode_out[0] = (nonbin == 0) ? 0 : ((nonfloat == 0) ? 2 : 1);
    return;
  }
  if (b <= 2) {
    const float* W = (b == 1) ? Wi : Wf;
    u16* WT = (b == 1) ? WiT : WfT;
    for (int o = t; o < 4096; o += 256) {
      int k = o >> 6, n = o & 63;
      WT[n * 64 + k] = (u16)f2bf(W[k * 64 + n]);
    }
    return;
  }
  int l = b - 3;                      // 0,1
  const float* Wu2 = upd_W + l * 8192 + 4096;
  if (t < 64) {
    float acc = 0.f;
    for (int j = 0; j < 64; ++j) acc = fmaf(msg_b[l * 64 + j], Wu2[j * 64 + t], acc);
    C1[l * 64 + t] = acc;
  }
}

// ============================ CSR scans + fill ============================
__global__ void k_scan_a(const int* cnt, int* blockSums) {
  __shared__ int sd[256];
  int t = threadIdx.x;
  int base = blockIdx.x * 1024 + t * 4;
  int s = 0;
  #pragma unroll
  for (int j = 0; j < 4; ++j) {
    int i = base + j;
    if (i < NN) s += cnt[i];
  }
  sd[t] = s;
  __syncthreads();
  for (int off = 128; off > 0; off >>= 1) {
    if (t < off) sd[t] += sd[t + off];
    __syncthreads();
  }
  if (t == 0) blockSums[blockIdx.x] = sd[0];
}

__global__ void k_scan_b(int* blockSums, int nb, int* total_out) {
  __shared__ int sd[128];
  int t = threadIdx.x;
  int v = (t < nb) ? blockSums[t] : 0;
  sd[t] = v;
  __syncthreads();
  for (int off = 1; off < 128; off <<= 1) {
    int x = (t >= off) ? sd[t - off] : 0;
    __syncthreads();
    sd[t] += x;
    __syncthreads();
  }
  if (t < nb) blockSums[t] = sd[t] - v;
  if (t == 0) total_out[0] = sd[127];
}

__global__ void k_scan_c(const int* cnt, const int* blockOffs, int* row_ptr,
                         int* cursor, float* cinv) {
  __shared__ int sd[256];
  int t = threadIdx.x;
  int base = blockIdx.x * 1024 + t * 4;
  int v[4], s = 0;
  #pragma unroll
  for (int j = 0; j < 4; ++j) {
    int i = base + j;
    v[j] = (i < NN) ? cnt[i] : 0;
    s += v[j];
  }
  sd[t] = s;
  __syncthreads();
  for (int off = 1; off < 256; off <<= 1) {
    int x = (t >= off) ? sd[t - off] : 0;
    __syncthreads();
    sd[t] += x;
    __syncthreads();
  }
  int excl = sd[t] - s + blockOffs[blockIdx.x];
  #pragma unroll
  for (int j = 0; j < 4; ++j) {
    int i = base + j;
    if (i < NN) {
      row_ptr[i] = excl;
      cursor[i] = excl;
      cinv[i] = 1.0f / fmaxf((float)v[j], 1.0f);
    }
    excl += v[j];
  }
}

__global__ void k_fill(const void* mask, const int* src, const int* dst,
                       int* cursor, int* col, const int* mode_p) {
  int e = blockIdx.x * 256 + threadIdx.x;
  if (e >= EE) return;
  if (mask_at(mask, e, *mode_p)) {
    int p = atomicAdd(&cursor[dst[e]], 1);
    col[p] = src[e];
  }
}

// ============================ MFMA helpers ============================
// Wave w owns rows [w*16, w*16+16). A-frag: A[m=lane&15][k=quad*8+j].
// B-frag from padded LDS. C/D: col=lane&15 (+nt*16), row=quad*4+reg.
__device__ __forceinline__ void mm4(const u16* lW, int m16, int q,
                                    bf16x8 a0, bf16x8 a1, f32x4 (&acc)[4]) {
  #pragma unroll
  for (int nt = 0; nt < 4; ++nt) {
    const u16* wp = lW + (nt * 16 + m16) * WSTR + q * 8;
    bf16x8 b0 = *(const bf16x8*)(wp);
    bf16x8 b1 = *(const bf16x8*)(wp + 32);
    acc[nt] = __builtin_amdgcn_mfma_f32_16x16x32_bf16(a0, b0, acc[nt], 0, 0, 0);
    acc[nt] = __builtin_amdgcn_mfma_f32_16x16x32_bf16(a1, b1, acc[nt], 0, 0, 0);
  }
}

// stage 64x64 bf16 weight (unpadded global) into padded LDS (stride WSTR)
__device__ __forceinline__ void stage_W(const u16* __restrict__ WT, u16* lW) {
  int t = threadIdx.x;
  int r = t >> 2, seg = (t & 3) * 16;
  const uint4* p = (const uint4*)(WT + r * 64 + seg);
  uint4 a = p[0], b = p[1];
  *(uint4*)(lW + r * WSTR + seg) = a;
  *(uint4*)(lW + r * WSTR + seg + 8) = b;
}

// ============================ input projection block (register-direct) ============================
// Thread t computes exactly ITS MFMA A-fragment elements: row arow=w*16+m16,
// k-segments [q*8, q*8+8) and [q*8+32, q*8+40) — no lT stage, no transpose.
__device__ __forceinline__ void input_block(int tile, int inst,
                                            const float* __restrict__ x,
                                            const u16* __restrict__ WiT,
                                            const float* __restrict__ bi,
                                            u16* __restrict__ HoutB,
                                            u16* lW, float* lB) {
  int t = threadIdx.x;
  stage_W(WiT, lW);
  if (t < 64) lB[t] = bi[t];
  int R0 = tile * 64;
  int l = t & 63, w = t >> 6;
  int m16 = l & 15, q = l >> 4;
  int arow = w * 16 + m16;
  int gra = R0 + arow;
  float v[16];
  if (gra < NN) {
    const float4* p0 = (const float4*)(x + (size_t)gra * 64 + q * 8);
    const float4* p1 = (const float4*)(x + (size_t)gra * 64 + q * 8 + 32);
    float4 a = p0[0], b = p0[1], c = p1[0], d = p1[1];
    v[0] = a.x;  v[1] = a.y;  v[2] = a.z;  v[3] = a.w;
    v[4] = b.x;  v[5] = b.y;  v[6] = b.z;  v[7] = b.w;
    v[8] = c.x;  v[9] = c.y;  v[10] = c.z; v[11] = c.w;
    v[12] = d.x; v[13] = d.y; v[14] = d.z; v[15] = d.w;
    if (inst > 0) {
      int s = inst - 1;
      #pragma unroll
      for (int j = 0; j < 8; ++j) v[j] += noise_val(s, gra, q * 8 + j);
      #pragma unroll
      for (int j = 0; j < 8; ++j) v[8 + j] += noise_val(s, gra, q * 8 + 32 + j);
    }
  } else {
    #pragma unroll
    for (int j = 0; j < 16; ++j) v[j] = 0.f;
  }
  union UB { uint32_t u[4]; bf16x8 vv; };
  UB ua, ub;
  #pragma unroll
  for (int jj = 0; jj < 4; ++jj) {
    ua.u[jj] = f2bf(v[2 * jj]) | (f2bf(v[2 * jj + 1]) << 16);
    ub.u[jj] = f2bf(v[8 + 2 * jj]) | (f2bf(v[8 + 2 * jj + 1]) << 16);
  }
  __syncthreads();   // lW staged
  f32x4 acc[4] = {{0.f, 0.f, 0.f, 0.f}, {0.f, 0.f, 0.f, 0.f},
                  {0.f, 0.f, 0.f, 0.f}, {0.f, 0.f, 0.f, 0.f}};
  mm4(lW, m16, q, ua.vv, ub.vv, acc);
  u16* Hout = HoutB + (size_t)inst * SLAB;
  #pragma unroll
  for (int nt = 0; nt < 4; ++nt) {
    int c = nt * 16 + m16;
    #pragma unroll
    for (int r_ = 0; r_ < 4; ++r_) {
      int row = w * 16 + q * 4 + r_;
      int gr = R0 + row;
      if (gr < NN) {
        float z = fmaxf(acc[nt][r_] + lB[c], 0.f);
        Hout[(size_t)gr * 64 + c] = (u16)f2bf(z);
      }
    }
  }
}

// ============================ mega: count ⊕ input (interleaved) ⊕ prep — ONE kernel ============================
// Champion (R11): single-kernel packing + 1:1 interleave + register-direct input.
// Count blocks (memory/atomic) and input blocks (VALU noise) are co-resident
// throughout the first 6250 blocks; input LDS is 9.5 KB (no lT) for occupancy.
__global__ __launch_bounds__(256) void k_mega(
    const void* __restrict__ mask, const int* __restrict__ dst,
    int* __restrict__ cnt, const int* __restrict__ mode_p,
    const float* __restrict__ x, const u16* __restrict__ WiT,
    const float* __restrict__ bi, u16* __restrict__ HoutB,
    const float* __restrict__ msg_W, const float* __restrict__ upd_W,
    u16* __restrict__ Wu1T, u16* __restrict__ A1T, u16* __restrict__ A2T) {
  __shared__ __align__(16) u16 lW[64 * WSTR];
  __shared__ float lB[64];
  int t = threadIdx.x;
  int bid = blockIdx.x;

  int idx = -1;
  if (bid < 6250) {
    if ((bid & 1) == 0) {                    // ---- edge count ----
      int e = (bid >> 1) * 256 + t;
      if (e < EE && mask_at(mask, e, *mode_p)) atomicAdd(&cnt[dst[e]], 1);
      return;
    }
    idx = bid >> 1;                          // input 0..3124
  } else if (bid < 10940) {
    idx = 3125 + (bid - 6250);               // input 3125..7814
  }
  if (idx >= 0) {
    input_block(idx % GEMM_BX, idx / GEMM_BX, x, WiT, bi, HoutB, lW, lB);
    return;
  }
  // ---- A1T/A2T/Wu1T fold (split-K), 128 blocks ----
  int blk = bid - 10940;
  int l = blk >> 6, b = blk & 63;
  const float* WmT = msg_W + l * 8192;
  const float* WmB = WmT + 4096;
  const float* Wu1 = upd_W + l * 8192;
  const float* Wu2 = Wu1 + 4096;
  float* sd1 = (float*)lW;                   // alias: 2 KB of lW
  float* sd2 = sd1 + 256;
  int a = t & 63, part = t >> 6;
  float a1 = 0.f, a2 = 0.f;
  #pragma unroll
  for (int jj = 0; jj < 16; ++jj) {
    int j = part * 16 + jj;
    float w2 = Wu2[j * 64 + b];
    a1 = fmaf(WmT[a * 64 + j], w2, a1);
    a2 = fmaf(WmB[a * 64 + j], w2, a2);
  }
  sd1[part * 64 + a] = a1;
  sd2[part * 64 + a] = a2;
  __syncthreads();
  if (t < 64) {
    float s1 = sd1[t] + sd1[64 + t] + sd1[128 + t] + sd1[192 + t];
    float s2 = sd2[t] + sd2[64 + t] + sd2[128 + t] + sd2[192 + t];
    int o = l * 4096 + b * 64 + t;
    A1T[o] = (u16)f2bf(s1);
    A2T[o] = (u16)f2bf(s2);
    Wu1T[o] = (u16)f2bf(Wu1[t * 64 + b]);
  }
}

// ============================ layer (2 instances/block, R2-champion) ============================
__global__ __launch_bounds__(256) void k_layer(const u16* __restrict__ HinB,
                                               u16* __restrict__ HoutB,
                                               const int* __restrict__ row_ptr,
                                               const int* __restrict__ col,
                                               const float* __restrict__ cinv,
                                               const u16* __restrict__ Wu1T,
                                               const u16* __restrict__ A1T,
                                               const u16* __restrict__ A2T,
                                               const float* __restrict__ b0,
                                               const float* __restrict__ c1) {
  __shared__ __align__(16) u16 lS0[64 * WSTR];
  __shared__ __align__(16) u16 lS1[64 * WSTR];
  __shared__ __align__(16) u16 lW[64 * WSTR];   // aliased as edge-index buffer pre-GEMM
  __shared__ float lB[128];
  __shared__ float lG[64];
  __shared__ int   lRP[65];
  int* lEdge = (int*)lW;                         // EDGE_CAP ints

  int t = threadIdx.x;
  int R0 = blockIdx.x * 64;
  int instBase = blockIdx.y * 2;
  bool two = (instBase + 1) < 5;
  const u16* Hin0 = HinB + (size_t)instBase * SLAB;
  const u16* Hin1 = Hin0 + (two ? SLAB : 0);
  u16* Hout0 = HoutB + (size_t)instBase * SLAB;
  u16* Hout1 = Hout0 + SLAB;

  if (t < 65) {
    int idx = R0 + t;
    if (idx > NN) idx = NN;
    lRP[t] = row_ptr[idx];
  }
  if (t < 64) {
    lB[t] = b0[t];
    lB[64 + t] = c1[t];
  }
  __syncthreads();

  int e0 = lRP[0];
  int nE = lRP[64] - e0;
  bool inLds = (nE <= EDGE_CAP);
  if (inLds) {
    for (int i = t; i < nE; i += 256) lEdge[i] = col[e0 + i];
  }
  if (t < 64) lG[t] = (lRP[t + 1] > lRP[t]) ? 1.f : 0.f;
  __syncthreads();

  // ---- gather: 8 lanes per row (uint4 = 16 B/lane), 32 rows per pass ----
  {
    int sub = t >> 3, lane8 = t & 7;
    int f0 = lane8 * 8;                       // u16 offset (16 B segment)
    const u16* hb0 = Hin0 + f0;
    const u16* hb1 = Hin1 + f0;
    #pragma unroll
    for (int bb = 0; bb < 2; ++bb) {
      int r = bb * 32 + sub;
      int n = R0 + r;
      float g[8], h[8];
      #pragma unroll
      for (int j = 0; j < 8; ++j) { g[j] = 0.f; h[j] = 0.f; }
      if (n < NN) {
        int e = lRP[r], end = lRP[r + 1];
        int last = end - 1;
        for (; e < end; e += 4) {
          int idx4[4];
          #pragma unroll
          for (int j = 0; j < 4; ++j) {
            int ee = e + j;
            ee = (ee < last) ? ee : last;
            idx4[j] = inLds ? lEdge[ee - e0] : col[ee];
          }
          uint4 P[4];
          #pragma unroll
          for (int j = 0; j < 4; ++j)
            P[j] = *(const uint4*)(hb0 + ((unsigned)idx4[j] << 6));
          uint4 Q[4];
          if (two) {
            #pragma unroll
            for (int j = 0; j < 4; ++j)
              Q[j] = *(const uint4*)(hb1 + ((unsigned)idx4[j] << 6));
          }
          #pragma unroll
          for (int j = 1; j < 4; ++j) {
            bool ok = (e + j) < end;
            P[j].x = ok ? P[j].x : 0u;
            P[j].y = ok ? P[j].y : 0u;
            P[j].z = ok ? P[j].z : 0u;
            P[j].w = ok ? P[j].w : 0u;
            if (two) {
              Q[j].x = ok ? Q[j].x : 0u;
              Q[j].y = ok ? Q[j].y : 0u;
              Q[j].z = ok ? Q[j].z : 0u;
              Q[j].w = ok ? Q[j].w : 0u;
            }
          }
          #pragma unroll
          for (int j = 0; j < 4; ++j) {
            uint4 v = P[j];
            g[0] += __uint_as_float(v.x << 16);
            g[1] += __uint_as_float(v.x & 0xffff0000u);
            g[2] += __uint_as_float(v.y << 16);
            g[3] += __uint_as_float(v.y & 0xffff0000u);
            g[4] += __uint_as_float(v.z << 16);
            g[5] += __uint_as_float(v.z & 0xffff0000u);
            g[6] += __uint_as_float(v.w << 16);
            g[7] += __uint_as_float(v.w & 0xffff0000u);
          }
          if (two) {
            #pragma unroll
            for (int j = 0; j < 4; ++j) {
              uint4 v = Q[j];
              h[0] += __uint_as_float(v.x << 16);
              h[1] += __uint_as_float(v.x & 0xffff0000u);
              h[2] += __uint_as_float(v.y << 16);
              h[3] += __uint_as_float(v.y & 0xffff0000u);
              h[4] += __uint_as_float(v.z << 16);
              h[5] += __uint_as_float(v.z & 0xffff0000u);
              h[6] += __uint_as_float(v.w << 16);
              h[7] += __uint_as_float(v.w & 0xffff0000u);
            }
          }
        }
        float ci = cinv[n];
        #pragma unroll
        for (int j = 0; j < 8; ++j) { g[j] *= ci; h[j] *= ci; }
      }
      uint4 pk;
      pk.x = f2bf(g[0]) | (f2bf(g[1]) << 16);
      pk.y = f2bf(g[2]) | (f2bf(g[3]) << 16);
      pk.z = f2bf(g[4]) | (f2bf(g[5]) << 16);
      pk.w = f2bf(g[6]) | (f2bf(g[7]) << 16);
      *(uint4*)(lS0 + r * WSTR + f0) = pk;
      if (two) {
        uint4 pk2;
        pk2.x = f2bf(h[0]) | (f2bf(h[1]) << 16);
        pk2.y = f2bf(h[2]) | (f2bf(h[3]) << 16);
        pk2.z = f2bf(h[4]) | (f2bf(h[5]) << 16);
        pk2.w = f2bf(h[6]) | (f2bf(h[7]) << 16);
        *(uint4*)(lS1 + r * WSTR + f0) = pk2;
      }
    }
  }
  __syncthreads();   // lS0/lS1 done; lEdge dead — lW free for weights

  int l = t & 63, w = t >> 6;
  int m16 = l & 15, q = l >> 4;
  int arow = w * 16 + m16;
  int gra = R0 + arow;
  bf16x8 zz = {0, 0, 0, 0, 0, 0, 0, 0};
  bf16x8 fa0_0 = zz, fa1_0 = zz, fa0_1 = zz, fa1_1 = zz;
  if (gra < NN) {
    const u16* ap = Hin0 + (size_t)gra * 64 + q * 8;
    fa0_0 = *(const bf16x8*)(ap);
    fa1_0 = *(const bf16x8*)(ap + 32);
    if (two) {
      const u16* ap1 = Hin1 + (size_t)gra * 64 + q * 8;
      fa0_1 = *(const bf16x8*)(ap1);
      fa1_1 = *(const bf16x8*)(ap1 + 32);
    }
  }

  stage_W(Wu1T, lW);
  __syncthreads();

  float gA = lG[arow];
  f32x4 acc0[4] = {{0.f, 0.f, 0.f, 0.f}, {0.f, 0.f, 0.f, 0.f},
                   {0.f, 0.f, 0.f, 0.f}, {0.f, 0.f, 0.f, 0.f}};
  f32x4 acc1[4] = {{0.f, 0.f, 0.f, 0.f}, {0.f, 0.f, 0.f, 0.f},
                   {0.f, 0.f, 0.f, 0.f}, {0.f, 0.f, 0.f, 0.f}};
  mm4(lW, m16, q, fa0_0, fa1_0, acc0);            // H @ Wu1
  if (two) mm4(lW, m16, q, fa0_1, fa1_1, acc1);
  __syncthreads();
  stage_W(A1T, lW);
  __syncthreads();
  {
    bf16x8 ga0 = (gA != 0.f) ? fa0_0 : zz;
    bf16x8 ga1 = (gA != 0.f) ? fa1_0 : zz;
    mm4(lW, m16, q, ga0, ga1, acc0);              // g * (H @ A1)
    if (two) {
      bf16x8 gb0 = (gA != 0.f) ? fa0_1 : zz;
      bf16x8 gb1 = (gA != 0.f) ? fa1_1 : zz;
      mm4(lW, m16, q, gb0, gb1, acc1);
    }
  }
  __syncthreads();
  stage_W(A2T, lW);
  __syncthreads();
  {
    const u16* sRow = lS0 + arow * WSTR + q * 8;
    bf16x8 fs0 = *(const bf16x8*)(sRow);
    bf16x8 fs1 = *(const bf16x8*)(sRow + 32);
    mm4(lW, m16, q, fs0, fs1, acc0);              // (cinv*S) @ A2
    if (two) {
      const u16* sRow1 = lS1 + arow * WSTR + q * 8;
      bf16x8 ft0 = *(const bf16x8*)(sRow1);
      bf16x8 ft1 = *(const bf16x8*)(sRow1 + 32);
      mm4(lW, m16, q, ft0, ft1, acc1);
    }
  }
  #pragma unroll
  for (int nt = 0; nt < 4; ++nt) {
    int c = nt * 16 + m16;
    #pragma unroll
    for (int r_ = 0; r_ < 4; ++r_) {
      int row = w * 16 + q * 4 + r_;
      int gr = R0 + row;
      if (gr < NN) {
        float bias = lB[c] + lG[row] * lB[64 + c];
        float v0 = fmaxf(acc0[nt][r_] + bias, 0.f);
        Hout0[(size_t)gr * 64 + c] = (u16)f2bf(v0);
        if (two) {
          float v1 = fmaxf(acc1[nt][r_] + bias, 0.f);
          Hout1[(size_t)gr * 64 + c] = (u16)f2bf(v1);
        }
      }
    }
  }
}

// ============================ final projection + variance (register-direct A-frags) ============================
__global__ __launch_bounds__(256) void k_final(const u16* __restrict__ HinB,
                                               const u16* __restrict__ WfT,
                                               const float* __restrict__ bfv,
                                               float* __restrict__ outCausal,
                                               float* __restrict__ out_u) {
  __shared__ __align__(16) u16 lW[64 * WSTR];
  __shared__ float lB[64];
  int t = threadIdx.x;
  int R0 = blockIdx.x * 64;
  stage_W(WfT, lW);
  if (t < 64) lB[t] = bfv[t];
  int l = t & 63, w = t >> 6;
  int m16 = l & 15, q = l >> 4;
  int arow = w * 16 + m16;
  int gra = R0 + arow;
  bf16x8 zz = {0, 0, 0, 0, 0, 0, 0, 0};
  float s1[16], s2[16];
  #pragma unroll
  for (int j = 0; j < 16; ++j) { s1[j] = 0.f; s2[j] = 0.f; }
  __syncthreads();   // lW staged

  for (int inst = 0; inst < 5; ++inst) {
    bf16x8 fa0 = zz, fa1 = zz;
    if (gra < NN) {
      const u16* ap = HinB + (size_t)inst * SLAB + (size_t)gra * 64 + q * 8;
      fa0 = *(const bf16x8*)(ap);
      fa1 = *(const bf16x8*)(ap + 32);
    }
    f32x4 acc[4] = {{0.f, 0.f, 0.f, 0.f}, {0.f, 0.f, 0.f, 0.f},
                    {0.f, 0.f, 0.f, 0.f}, {0.f, 0.f, 0.f, 0.f}};
    mm4(lW, m16, q, fa0, fa1, acc);
    #pragma unroll
    for (int nt = 0; nt < 4; ++nt) {
      int c = nt * 16 + m16;
      #pragma unroll
      for (int r_ = 0; r_ < 4; ++r_) {
        float z = acc[nt][r_] + lB[c];
        if (inst == 0) {
          int gr = R0 + w * 16 + q * 4 + r_;
          if (gr < NN) outCausal[(size_t)gr * 64 + c] = z;
        } else {
          s1[nt * 4 + r_] += z;
          s2[nt * 4 + r_] = fmaf(z, z, s2[nt * 4 + r_]);
        }
      }
    }
  }
  #pragma unroll
  for (int r_ = 0; r_ < 4; ++r_) {
    float pr = 0.f;
    #pragma unroll
    for (int nt = 0; nt < 4; ++nt) {
      float a = s1[nt * 4 + r_];
      pr += s2[nt * 4 + r_] - 0.25f * a * a;
    }
    #pragma unroll
    for (int msk = 1; msk < 16; msk <<= 1)
      pr += __shfl_xor(pr, msk, 64);
    if (m16 == 0) {
      int gr = R0 + w * 16 + q * 4 + r_;
      if (gr < NN) out_u[gr] = fmaxf(pr * (1.0f / 3.0f), 1e-6f);
    }
  }
}

// ============================ launch ============================
extern "C" void kernel_launch(void* const* d_in, const int* in_sizes, int n_in,
                              void* d_out, int out_size, void* d_ws, size_t ws_size,
                              hipStream_t stream) {
  const float* x      = (const float*)d_in[0];
  const int*   eidx   = (const int*)d_in[1];
  const void*  mask   = d_in[2];
  const float* Wi     = (const float*)d_in[3];
  const float* bi     = (const float*)d_in[4];
  const float* msg_W  = (const float*)d_in[5];
  const float* msg_b  = (const float*)d_in[6];
  const float* upd_W  = (const float*)d_in[7];
  const float* upd_b  = (const float*)d_in[8];
  const float* Wf     = (const float*)d_in[9];
  const float* bfv    = (const float*)d_in[10];

  const int* src = eidx;
  const int* dst = eidx + EE;

  char* ws = (char*)d_ws;
  size_t off = 0;
  auto alloc = [&](size_t bytes) -> void* {
    void* p = ws + off;
    off += (bytes + 255) & ~(size_t)255;
    return p;
  };

  int*   cnt     = (int*)alloc(NN * sizeof(int));
  float* cinv    = (float*)alloc(NN * sizeof(float));
  int*   row_ptr = (int*)alloc((NN + 1) * sizeof(int));
  int*   cursor  = (int*)alloc(NN * sizeof(int));
  int*   col     = (int*)alloc(EE * sizeof(int));
  int*   bsums   = (int*)alloc(128 * sizeof(int));
  int*   mode_p  = (int*)alloc(sizeof(int));
  u16*   Wu1T    = (u16*)alloc(2 * 4096 * sizeof(u16));
  u16*   A1T     = (u16*)alloc(2 * 4096 * sizeof(u16));
  u16*   A2T     = (u16*)alloc(2 * 4096 * sizeof(u16));
  u16*   WiT     = (u16*)alloc(4096 * sizeof(u16));
  u16*   WfT     = (u16*)alloc(4096 * sizeof(u16));
  float* C1      = (float*)alloc(2 * 64 * sizeof(float));
  u16*   HA      = (u16*)alloc(5 * SLAB * sizeof(u16));   // 64 MB
  u16*   HB      = (u16*)alloc(5 * SLAB * sizeof(u16));   // 64 MB

  float* out_causal = (float*)d_out;
  float* out_u      = (float*)d_out + SLAB;

  // ---- pre: detect + WiT/WfT transpose + C1 + cnt zero (103 blocks) ----
  k_pre<<<103, 256, 0, stream>>>((const unsigned*)mask, mode_p, Wi, Wf,
                                 msg_b, upd_W, WiT, WfT, C1, cnt);

  // ---- mega: edge count ⊕ input (interleaved) ⊕ weight fold ----
  k_mega<<<MG_TOTAL, 256, 0, stream>>>(mask, dst, cnt, mode_p,
                                       x, WiT, bi, HA,
                                       msg_W, upd_W, Wu1T, A1T, A2T);

  // ---- CSR scans + fill ----
  const int SCAN_BLKS = (NN + 1023) / 1024;  // 98
  k_scan_a<<<SCAN_BLKS, 256, 0, stream>>>(cnt, bsums);
  k_scan_b<<<1, 128, 0, stream>>>(bsums, SCAN_BLKS, row_ptr + NN);
  k_scan_c<<<SCAN_BLKS, 256, 0, stream>>>(cnt, bsums, row_ptr, cursor, cinv);
  k_fill<<<EE / 256, 256, 0, stream>>>(mask, src, dst, cursor, col, mode_p);

  // ---- 2 GNN layers (instance pairs) + final ----
  dim3 gl(GEMM_BX, 3);   // instance pairs {0,1},{2,3},{4}
  k_layer<<<gl, 256, 0, stream>>>(HA, HB, row_ptr, col, cinv,
                                  Wu1T, A1T, A2T, upd_b, C1);
  k_layer<<<gl, 256, 0, stream>>>(HB, HA, row_ptr, col, cinv,
                                  Wu1T + 4096, A1T + 4096, A2T + 4096,
                                  upd_b + 64, C1 + 64);
  k_final<<<GEMM_BX, 256, 0, stream>>>(HA, WfT, bfv, out_causal, out_u);

  (void)in_sizes; (void)n_in; (void)out_size; (void)ws_size;
}